// Round 1
// baseline (248.199 us; speedup 1.0000x reference)
//
#include <hip/hip_runtime.h>

#define HW 512
#define CH 3
#define KK 9
#define BS 8
#define TW 32
#define TH 8

// ws layout (floats):
// [0, 675)    : W5   [c*25+ey*5+ex][o]   scaled 5x5 folded weights (input part)
// [675, 918)  : W3   [c*9+dy*3+dx][o]    scaled 3x3 weights (input0 part)
// [918, 927)  : shift[o]
// [927, 3114) : Wfull[ic][dy*3+dx][o]    scaled raw conv weights (border kernel)

__global__ __launch_bounds__(256) void prep_kernel(
    const float* __restrict__ conv_w, const float* __restrict__ gamma,
    const float* __restrict__ beta, const float* __restrict__ mean,
    const float* __restrict__ var, float* __restrict__ ws) {
  const int tid = threadIdx.x;
  // W5: fold (oy,ox) x (dy,dx) pairs with oy+dy==ey, ox+dx==ex; exclude replaced rows
  for (int t = tid; t < 675; t += 256) {
    int o = t % 9, tap = t / 9;
    int c = tap / 25, r = tap % 25, ey = r / 5, ex = r % 5;
    float s = gamma[o] * rsqrtf(var[o] + 1e-5f);
    float sum = 0.f;
    for (int dy = 0; dy < 3; ++dy) {
      int oy = ey - dy; if (oy < 0 || oy > 2) continue;
      for (int dx = 0; dx < 3; ++dx) {
        int ox = ex - dx; if (ox < 0 || ox > 2) continue;
        int off = oy * 3 + ox;
        if (c == 0 && off >= 4 && off <= 6) continue;  // rows replaced by input0
        sum += conv_w[((o * 27 + c * 9 + off) * 3 + dy) * 3 + dx];
      }
    }
    ws[t] = s * sum;
  }
  // W3: input0 channels are im2col rows 4,5,6 -> ic = 4 + c
  for (int t = tid; t < 243; t += 256) {
    int o = t % 9, tap = t / 9;
    int c = tap / 9, r = tap % 9, dy = r / 3, dx = r % 3;
    float s = gamma[o] * rsqrtf(var[o] + 1e-5f);
    ws[675 + t] = s * conv_w[((o * 27 + 4 + c) * 3 + dy) * 3 + dx];
  }
  for (int o = tid; o < 9; o += 256) {
    float s = gamma[o] * rsqrtf(var[o] + 1e-5f);
    ws[918 + o] = beta[o] - mean[o] * s;
  }
  for (int t = tid; t < 2187; t += 256) {
    int o = t % 9, q = t / 9;
    int ic = q / 9, r = q % 9, dy = r / 3, dx = r % 3;
    float s = gamma[o] * rsqrtf(var[o] + 1e-5f);
    ws[927 + t] = s * conv_w[((o * 27 + ic) * 3 + dy) * 3 + dx];
  }
}

__global__ __launch_bounds__(256) void main_kernel(
    const float* __restrict__ kern, const float* __restrict__ input,
    const float* __restrict__ input0, const float* __restrict__ ws,
    float* __restrict__ out) {
  __shared__ float in_t[3][TH + 4][TW + 4];    // pad-2 halo for 5x5
  __shared__ float in0_t[3][TH + 2][TW + 2];   // pad-1 halo for 3x3
  const int tid = threadIdx.x;
  const int b = blockIdx.z;
  const int x0 = blockIdx.x * TW, y0 = blockIdx.y * TH;
  const float* inp_b = input + (long)b * CH * HW * HW;
  const float* inp0_b = input0 + (long)b * CH * HW * HW;

  float* lin = &in_t[0][0][0];
  for (int i = tid; i < 3 * (TH + 4) * (TW + 4); i += 256) {
    int c = i / ((TH + 4) * (TW + 4));
    int r = i % ((TH + 4) * (TW + 4));
    int ry = r / (TW + 4), rx = r % (TW + 4);
    int gy = y0 + ry - 2, gx = x0 + rx - 2;
    float v = 0.f;
    if ((unsigned)gy < HW && (unsigned)gx < HW) v = inp_b[(c * HW + gy) * HW + gx];
    lin[i] = v;
  }
  float* lin0 = &in0_t[0][0][0];
  for (int i = tid; i < 3 * (TH + 2) * (TW + 2); i += 256) {
    int c = i / ((TH + 2) * (TW + 2));
    int r = i % ((TH + 2) * (TW + 2));
    int ry = r / (TW + 2), rx = r % (TW + 2);
    int gy = y0 + ry - 1, gx = x0 + rx - 1;
    float v = 0.f;
    if ((unsigned)gy < HW && (unsigned)gx < HW) v = inp0_b[(c * HW + gy) * HW + gx];
    lin0[i] = v;
  }
  __syncthreads();

  const int tx = tid & 31, ty = tid >> 5;
  const int X = x0 + tx, Y = y0 + ty;
  float acc[9];
#pragma unroll
  for (int o = 0; o < 9; ++o) acc[o] = 0.f;

#pragma unroll
  for (int c = 0; c < 3; ++c)
#pragma unroll
    for (int ey = 0; ey < 5; ++ey)
#pragma unroll
      for (int ex = 0; ex < 5; ++ex) {
        float v = in_t[c][ty + ey][tx + ex];
        const float* w = ws + (c * 25 + ey * 5 + ex) * 9;
#pragma unroll
        for (int o = 0; o < 9; ++o) acc[o] = fmaf(w[o], v, acc[o]);
      }

#pragma unroll
  for (int c = 0; c < 3; ++c)
#pragma unroll
    for (int ey = 0; ey < 3; ++ey)
#pragma unroll
      for (int ex = 0; ex < 3; ++ex) {
        float v = in0_t[c][ty + ey][tx + ex];
        const float* w = ws + 675 + (c * 9 + ey * 3 + ex) * 9;
#pragma unroll
        for (int o = 0; o < 9; ++o) acc[o] = fmaf(w[o], v, acc[o]);
      }

  const float* kb = kern + (long)b * KK * (HW * HW) + Y * HW + X;
  float result = 0.f;
#pragma unroll
  for (int o = 0; o < 9; ++o)
    result = fmaf(kb[(long)o * (HW * HW)], acc[o] + ws[918 + o], result);
  out[((long)b * HW + Y) * HW + X] = result;
}

// Border frame (Y or X in {0, HW-1}): 5x5 folding invalid because the conv's
// intermediate pad-1 zeroing bites; recompute exactly from raw (masked) taps.
__global__ __launch_bounds__(256) void border_kernel(
    const float* __restrict__ kern, const float* __restrict__ input,
    const float* __restrict__ input0, const float* __restrict__ ws,
    float* __restrict__ out) {
  const int per_img = 4 * HW - 4;  // 2044
  int idx = blockIdx.x * blockDim.x + threadIdx.x;
  if (idx >= BS * per_img) return;
  int b = idx / per_img, p = idx % per_img;
  int X, Y;
  if (p < HW) { Y = 0; X = p; }
  else if (p < 2 * HW) { Y = HW - 1; X = p - HW; }
  else if (p < 3 * HW - 2) { X = 0; Y = p - 2 * HW + 1; }
  else { X = HW - 1; Y = p - (3 * HW - 2) + 1; }

  const float* inp_b = input + (long)b * CH * HW * HW;
  const float* inp0_b = input0 + (long)b * CH * HW * HW;
  float acc[9];
#pragma unroll
  for (int o = 0; o < 9; ++o) acc[o] = 0.f;

  for (int dy = 0; dy < 3; ++dy) {
    int yy = Y + dy - 1;
    if ((unsigned)yy >= HW) continue;          // conv's own zero pad
    for (int dx = 0; dx < 3; ++dx) {
      int xx = X + dx - 1;
      if ((unsigned)xx >= HW) continue;
      // input part: 27 im2col rows except the 3 replaced ones
      for (int c = 0; c < 3; ++c)
        for (int oy = 0; oy < 3; ++oy) {
          int iy = yy + oy - 1;
          for (int ox = 0; ox < 3; ++ox) {
            int off = oy * 3 + ox;
            if (c == 0 && off >= 4 && off <= 6) continue;
            int ix = xx + ox - 1;
            float v = 0.f;
            if ((unsigned)iy < HW && (unsigned)ix < HW)
              v = inp_b[(c * HW + iy) * HW + ix];
            const float* w = ws + 927 + ((c * 9 + off) * 9 + dy * 3 + dx) * 9;
#pragma unroll
            for (int o = 0; o < 9; ++o) acc[o] = fmaf(w[o], v, acc[o]);
          }
        }
      // input0 part (exact 3x3)
      for (int c = 0; c < 3; ++c) {
        float v = inp0_b[(c * HW + yy) * HW + xx];
        const float* w = ws + 675 + (c * 9 + dy * 3 + dx) * 9;
#pragma unroll
        for (int o = 0; o < 9; ++o) acc[o] = fmaf(w[o], v, acc[o]);
      }
    }
  }
  const float* kb = kern + (long)b * KK * (HW * HW) + Y * HW + X;
  float result = 0.f;
#pragma unroll
  for (int o = 0; o < 9; ++o)
    result = fmaf(kb[(long)o * (HW * HW)], acc[o] + ws[918 + o], result);
  out[((long)b * HW + Y) * HW + X] = result;
}

extern "C" void kernel_launch(void* const* d_in, const int* in_sizes, int n_in,
                              void* d_out, int out_size, void* d_ws, size_t ws_size,
                              hipStream_t stream) {
  const float* kern   = (const float*)d_in[0];
  const float* input  = (const float*)d_in[1];
  const float* input0 = (const float*)d_in[2];
  const float* conv_w = (const float*)d_in[3];
  const float* gamma  = (const float*)d_in[4];
  const float* beta   = (const float*)d_in[5];
  const float* mean   = (const float*)d_in[6];
  const float* var    = (const float*)d_in[7];
  float* out = (float*)d_out;
  float* ws  = (float*)d_ws;

  hipLaunchKernelGGL(prep_kernel, dim3(1), dim3(256), 0, stream,
                     conv_w, gamma, beta, mean, var, ws);
  dim3 grid(HW / TW, HW / TH, BS);
  hipLaunchKernelGGL(main_kernel, grid, dim3(256), 0, stream,
                     kern, input, input0, ws, out);
  int nb = (BS * (4 * HW - 4) + 255) / 256;
  hipLaunchKernelGGL(border_kernel, dim3(nb), dim3(256), 0, stream,
                     kern, input, input0, ws, out);
}

// Round 6
// 241.735 us; speedup vs baseline: 1.0267x; 1.0267x over previous
//
#include <hip/hip_runtime.h>

#define HW 512
#define CH 3
#define KK 9
#define BS 8
#define TW 64   // tile width in pixels
#define TH 16   // tile height in pixels
// threads: 16 x-threads (4 px each) x 16 y-threads = 256

// ws layout (floats):
// [0, 720)     : W5p  [(c*5+ey)*48 + ex*9 + o]   folded 5x5 weights, 48-padded groups
// [720, 1008)  : W3p  [c*96 + (ey*3+ex)*9 + o]   3x3 input0 weights, 96-padded groups
// [1008, 1017) : shift[o]
// [1024, 3211) : Wfull[((c*9+off)*9 + dy*3+dx)*9 + o]  raw scaled conv weights (border)

__global__ __launch_bounds__(256) void prep_kernel(
    const float* __restrict__ conv_w, const float* __restrict__ gamma,
    const float* __restrict__ beta, const float* __restrict__ mean,
    const float* __restrict__ var, float* __restrict__ ws) {
  const int tid = threadIdx.x;
  // W5p: fold (oy,ox)x(dy,dx) with oy+dy==ey, ox+dx==ex; exclude replaced rows
  for (int t = tid; t < 675; t += 256) {
    int o = t % 9, tap = t / 9;
    int c = tap / 25, r = tap % 25, ey = r / 5, ex = r % 5;
    float s = gamma[o] * rsqrtf(var[o] + 1e-5f);
    float sum = 0.f;
    for (int dy = 0; dy < 3; ++dy) {
      int oy = ey - dy; if (oy < 0 || oy > 2) continue;
      for (int dx = 0; dx < 3; ++dx) {
        int ox = ex - dx; if (ox < 0 || ox > 2) continue;
        int off = oy * 3 + ox;
        if (c == 0 && off >= 4 && off <= 6) continue;  // rows replaced by input0
        sum += conv_w[((o * 27 + c * 9 + off) * 3 + dy) * 3 + dx];
      }
    }
    ws[(c * 5 + ey) * 48 + ex * 9 + o] = s * sum;
  }
  // W3p: input0 channels are im2col rows 4,5,6 -> ic = 4 + c
  for (int t = tid; t < 243; t += 256) {
    int o = t % 9, tap = t / 9;
    int c = tap / 9, r = tap % 9;  // r = ey*3+ex
    float s = gamma[o] * rsqrtf(var[o] + 1e-5f);
    int ey = r / 3, ex = r % 3;
    ws[720 + c * 96 + r * 9 + o] =
        s * conv_w[((o * 27 + 4 + c) * 3 + ey) * 3 + ex];
  }
  for (int o = tid; o < 9; o += 256) {
    float s = gamma[o] * rsqrtf(var[o] + 1e-5f);
    ws[1008 + o] = beta[o] - mean[o] * s;
  }
  for (int t = tid; t < 2187; t += 256) {
    int o = t % 9, q = t / 9;
    int ic = q / 9, r = q % 9, dy = r / 3, dx = r % 3;
    float s = gamma[o] * rsqrtf(var[o] + 1e-5f);
    ws[1024 + t] = s * conv_w[((o * 27 + ic) * 3 + dy) * 3 + dx];
  }
}

__global__ __launch_bounds__(256) void main_kernel(
    const float* __restrict__ kern, const float* __restrict__ input,
    const float* __restrict__ input0, const float* __restrict__ ws,
    float* __restrict__ out) {
  __shared__ __align__(16) float in_t[3][TH + 4][TW + 4];   // pad-2 halo, rows 68f = 17x16B
  __shared__ __align__(16) float in0_t[3][TH + 2][TW + 4];  // pad-1 halo, padded to 68f
  const int tid = threadIdx.x;
  const int b = blockIdx.z;
  const int x0 = blockIdx.x * TW, y0 = blockIdx.y * TH;
  const float* inp_b = input + (long)b * CH * HW * HW;
  const float* inp0_b = input0 + (long)b * CH * HW * HW;

  float* lin = &in_t[0][0][0];
  for (int i = tid; i < 3 * (TH + 4) * (TW + 4); i += 256) {
    int c = i / ((TH + 4) * (TW + 4));
    int r = i % ((TH + 4) * (TW + 4));
    int ry = r / (TW + 4), rx = r % (TW + 4);
    int gy = y0 + ry - 2, gx = x0 + rx - 2;
    float v = 0.f;
    if ((unsigned)gy < HW && (unsigned)gx < HW) v = inp_b[(c * HW + gy) * HW + gx];
    lin[i] = v;
  }
  float* lin0 = &in0_t[0][0][0];
  for (int i = tid; i < 3 * (TH + 2) * (TW + 4); i += 256) {
    int c = i / ((TH + 2) * (TW + 4));
    int r = i % ((TH + 2) * (TW + 4));
    int ry = r / (TW + 4), rx = r % (TW + 4);
    int gy = y0 + ry - 1, gx = x0 + rx - 1;
    float v = 0.f;
    if ((unsigned)gy < HW && (unsigned)gx < HW) v = inp0_b[(c * HW + gy) * HW + gx];
    lin0[i] = v;
  }
  __syncthreads();

  const int tx = tid & 15, ty = tid >> 4;
  const int bx = tx * 4;           // first of 4 pixels in x
  const int Y = y0 + ty;

  float acc[9][4];
#pragma unroll
  for (int o = 0; o < 9; ++o)
#pragma unroll
    for (int p = 0; p < 4; ++p) acc[o][p] = 0.f;

  // ---- folded 5x5 (input part) ----
#pragma unroll 1
  for (int c = 0; c < 3; ++c) {
#pragma unroll 1
    for (int ey = 0; ey < 5; ++ey) {
      const float4 lo = *(const float4*)(&in_t[c][ty + ey][bx]);
      const float4 hi = *(const float4*)(&in_t[c][ty + ey][bx + 4]);
      const float win[8] = {lo.x, lo.y, lo.z, lo.w, hi.x, hi.y, hi.z, hi.w};
      const float* wg = ws + (c * 5 + ey) * 48;
#pragma unroll
      for (int ex = 0; ex < 5; ++ex)
#pragma unroll
        for (int o = 0; o < 9; ++o) {
          const float w = wg[ex * 9 + o];
#pragma unroll
          for (int p = 0; p < 4; ++p)
            acc[o][p] = fmaf(w, win[ex + p], acc[o][p]);
        }
    }
  }

  // ---- exact 3x3 (input0 part) ----
#pragma unroll 1
  for (int c = 0; c < 3; ++c) {
#pragma unroll 1
    for (int ey = 0; ey < 3; ++ey) {
      const float4 lo = *(const float4*)(&in0_t[c][ty + ey][bx]);
      const float4 hi = *(const float4*)(&in0_t[c][ty + ey][bx + 4]);
      const float win[8] = {lo.x, lo.y, lo.z, lo.w, hi.x, hi.y, hi.z, hi.w};
      const float* wg = ws + 720 + c * 96 + ey * 27;
#pragma unroll
      for (int ex = 0; ex < 3; ++ex)
#pragma unroll
        for (int o = 0; o < 9; ++o) {
          const float w = wg[ex * 9 + o];
#pragma unroll
          for (int p = 0; p < 4; ++p)
            acc[o][p] = fmaf(w, win[ex + p], acc[o][p]);
        }
    }
  }

  // ---- epilogue: + shift, weighted reduce against `kernel`, store ----
  const long hw2 = (long)HW * HW;
  const float* kb = kern + (long)b * KK * hw2 + (long)Y * HW + (x0 + bx);
  float res0 = 0.f, res1 = 0.f, res2 = 0.f, res3 = 0.f;
#pragma unroll
  for (int o = 0; o < 9; ++o) {
    const float sh = ws[1008 + o];
    const float4 k4 = *(const float4*)(kb + (long)o * hw2);
    res0 = fmaf(k4.x, acc[o][0] + sh, res0);
    res1 = fmaf(k4.y, acc[o][1] + sh, res1);
    res2 = fmaf(k4.z, acc[o][2] + sh, res2);
    res3 = fmaf(k4.w, acc[o][3] + sh, res3);
  }
  *(float4*)(out + ((long)b * HW + Y) * HW + (x0 + bx)) =
      make_float4(res0, res1, res2, res3);
}

// Border frame (Y or X in {0, HW-1}): 5x5 folding invalid there; recompute exact.
__global__ __launch_bounds__(256) void border_kernel(
    const float* __restrict__ kern, const float* __restrict__ input,
    const float* __restrict__ input0, const float* __restrict__ ws,
    float* __restrict__ out) {
  const int per_img = 4 * HW - 4;  // 2044
  int idx = blockIdx.x * blockDim.x + threadIdx.x;
  if (idx >= BS * per_img) return;
  int b = idx / per_img, p = idx % per_img;
  int X, Y;
  if (p < HW) { Y = 0; X = p; }
  else if (p < 2 * HW) { Y = HW - 1; X = p - HW; }
  else if (p < 3 * HW - 2) { X = 0; Y = p - 2 * HW + 1; }
  else { X = HW - 1; Y = p - (3 * HW - 2) + 1; }

  const float* inp_b = input + (long)b * CH * HW * HW;
  const float* inp0_b = input0 + (long)b * CH * HW * HW;
  float acc[9];
#pragma unroll
  for (int o = 0; o < 9; ++o) acc[o] = 0.f;

  for (int dy = 0; dy < 3; ++dy) {
    int yy = Y + dy - 1;
    if ((unsigned)yy >= HW) continue;          // conv's own zero pad
    for (int dx = 0; dx < 3; ++dx) {
      int xx = X + dx - 1;
      if ((unsigned)xx >= HW) continue;
      // input part: 27 im2col rows except the 3 replaced ones
      for (int c = 0; c < 3; ++c)
        for (int oy = 0; oy < 3; ++oy) {
          int iy = yy + oy - 1;
          for (int ox = 0; ox < 3; ++ox) {
            int off = oy * 3 + ox;
            if (c == 0 && off >= 4 && off <= 6) continue;
            int ix = xx + ox - 1;
            float v = 0.f;
            if ((unsigned)iy < HW && (unsigned)ix < HW)
              v = inp_b[(c * HW + iy) * HW + ix];
            const float* w = ws + 1024 + ((c * 9 + off) * 9 + dy * 3 + dx) * 9;
#pragma unroll
            for (int o = 0; o < 9; ++o) acc[o] = fmaf(w[o], v, acc[o]);
          }
        }
      // input0 part (exact 3x3)
      for (int c = 0; c < 3; ++c) {
        float v = inp0_b[(c * HW + yy) * HW + xx];
        const float* w = ws + 720 + c * 96 + (dy * 3 + dx) * 9;
#pragma unroll
        for (int o = 0; o < 9; ++o) acc[o] = fmaf(w[o], v, acc[o]);
      }
    }
  }
  const float* kb = kern + (long)b * KK * (HW * HW) + Y * HW + X;
  float result = 0.f;
#pragma unroll
  for (int o = 0; o < 9; ++o)
    result = fmaf(kb[(long)o * (HW * HW)], acc[o] + ws[1008 + o], result);
  out[((long)b * HW + Y) * HW + X] = result;
}

extern "C" void kernel_launch(void* const* d_in, const int* in_sizes, int n_in,
                              void* d_out, int out_size, void* d_ws, size_t ws_size,
                              hipStream_t stream) {
  const float* kern   = (const float*)d_in[0];
  const float* input  = (const float*)d_in[1];
  const float* input0 = (const float*)d_in[2];
  const float* conv_w = (const float*)d_in[3];
  const float* gamma  = (const float*)d_in[4];
  const float* beta   = (const float*)d_in[5];
  const float* mean   = (const float*)d_in[6];
  const float* var    = (const float*)d_in[7];
  float* out = (float*)d_out;
  float* ws  = (float*)d_ws;

  hipLaunchKernelGGL(prep_kernel, dim3(1), dim3(256), 0, stream,
                     conv_w, gamma, beta, mean, var, ws);
  dim3 grid(HW / TW, HW / TH, BS);
  hipLaunchKernelGGL(main_kernel, grid, dim3(256), 0, stream,
                     kern, input, input0, ws, out);
  int nb = (BS * (4 * HW - 4) + 255) / 256;
  hipLaunchKernelGGL(border_kernel, dim3(nb), dim3(256), 0, stream,
                     kern, input, input0, ws, out);
}